// Round 7
// baseline (314.784 us; speedup 1.0000x reference)
//
#include <hip/hip_runtime.h>
#include <hip/hip_bf16.h>

// Problem constants (match reference)
#define CIN_  128
#define H_    28
#define W_    28
#define COUT_ 32
#define B_    512
// GEMM view per (b,h): Y[32 x 28] = Wm[32 x 384] * Xwin[384 x 28]
// K order: kappa = tap*128 + channel, chunked in 12 chunks of 32.

typedef __attribute__((ext_vector_type(8))) short short8;  // 8 bf16 in 4 VGPRs
typedef __attribute__((ext_vector_type(4))) float f32x4;

__device__ __forceinline__ short f2bf(float f) {
    __hip_bfloat16 h = __float2bfloat16(f);    // RNE, single HW cvt
    union { __hip_bfloat16 h; short s; } u; u.h = h;
    return u.s;
}

// ---------------------------------------------------------------------------
// Pre-pass: build bf16 A-fragments of Wm in d_ws.
// Fragment f = mt*12 + hk; element (lane l, slot j):
//   Wm[jo = mt*16 + (l&15)][i = (hk&3)*32 + (l>>4)*8 + j][tap = hk>>2]
// ---------------------------------------------------------------------------
__global__ void prep_w_kernel(const float* __restrict__ w, short* __restrict__ wsA) {
    int t = blockIdx.x * 256 + threadIdx.x;      // 24*512 = 12288 threads
    int frag = t >> 9;
    int rem  = t & 511;
    int l = rem >> 3;
    int j = rem & 7;
    int mt = frag / 12;
    int kc = frag % 12;
    int tap = kc >> 2;
    int i  = (kc & 3) * 32 + (l >> 4) * 8 + j;
    int jo = mt * 16 + (l & 15);
    wsA[t] = f2bf(w[(jo * CIN_ + i) * 3 + tap]);
}

// ---------------------------------------------------------------------------
// Main kernel v7: WHOLE-BATCH blocks (zero cross-block cache-line sharing on
// both reads and writes) + double-buffered 4-row pipeline.
// grid 512 x 256 threads (4 waves, 2 blocks/CU, all resident). Block b owns
// x[b] (401 KB, read once, line-exclusive) and out[b] (100 KB, written once,
// line-exclusive -> no partial-line RMW at HBM).
// Per iteration g (0..6), rows h0 = 4g .. 4g+3, wave wv computes row h0+wv:
//   1. re-zero pad rows + cvt/scatter vb -> sb = lds[g&1]
//   2. prefetch loads for group g+1 into vb (stay in flight across barrier)
//   3. lgkmcnt(0); s_barrier            (no vmcnt drain!)
//   4. GEMM from sb (A-frags hoisted, held in regs across all iterations)
//   5. lgkmcnt(0); s_barrier            (own ds_reads drained before reuse)
//   6. gather acc -> arr (reuse sb); lgkmcnt(0); s_barrier
//   7. cooperative 16B-aligned f32x4 stores (4KB contiguous per instr)
// LDS row buffer: [wt 0..29][128 ch] bf16 XOR-swizzled:
//   (wt, i) at short index  wt*128 + (((i>>3) ^ (wt&15))<<3 | (i&7))
// wt = w + tap (w_real = wt-1). Rows 0,29 zero (padding). B-reads with
// wt in 30..33 feed discarded cols (wcol >= 28); clamp row to 29.
// ---------------------------------------------------------------------------
template<bool USE_WS>
__global__ __launch_bounds__(256, 2)
void conv_kernel(const float* __restrict__ x, const float* __restrict__ w,
                 const short* __restrict__ wsA, float* __restrict__ out) {
    __shared__ short lds[2][4][30 * CIN_];       // 61440 B
    const int tid = threadIdx.x;
    const int wv  = tid >> 6;
    const int l   = tid & 63;
    const int b   = blockIdx.x;

    const float* xb = x + (size_t)b * (CIN_ * H_ * W_);
    float*       ob = out + (size_t)b * (COUT_ * H_ * W_);

    // ---- issue group-0 loads ASAP ----
    f32x4 vb[14];
#pragma unroll
    for (int it = 0; it < 14; ++it) {
        int f4 = it * 256 + tid;                 // 0..3583
        int i  = f4 / 28;                        // channel
        int q  = f4 % 28;                        // quad within 448-B segment
        vb[it] = *reinterpret_cast<const f32x4*>(xb + i * (H_ * W_) + q * 4);
    }

    // ---- A fragments: all 24, loaded ONCE, live across all iterations ----
    short8 afrag[2][12];
    if (USE_WS) {
#pragma unroll
        for (int mt = 0; mt < 2; ++mt)
#pragma unroll
            for (int hk = 0; hk < 12; ++hk)
                afrag[mt][hk] = *reinterpret_cast<const short8*>(
                    wsA + (mt * 12 + hk) * 512 + l * 8);
    } else {
#pragma unroll
        for (int mt = 0; mt < 2; ++mt)
#pragma unroll
            for (int hk = 0; hk < 12; ++hk) {
                int tap = hk >> 2;
                int ib  = (hk & 3) * 32 + (l >> 4) * 8;
#pragma unroll
                for (int j = 0; j < 8; ++j)
                    afrag[mt][hk][j] = f2bf(w[((mt * 16 + (l & 15)) * CIN_ + ib + j) * 3 + tap]);
            }
    }

    for (int g = 0; g < 7; ++g) {
        short (*sb)[30 * CIN_] = lds[g & 1];
        const int h0 = g * 4;

        // ---- re-zero pad rows wt=0,29 of all 4 row-bufs (gather clobbers) --
        {
            int s   = tid * 4;                   // 0..1020
            int bi  = s >> 8;                    // row-buf 0..3
            int row = ((s >> 7) & 1) ? 29 : 0;
            int c   = s & 127;
            *reinterpret_cast<ulong1*>(&sb[bi][row * CIN_ + c]) = ulong1{0};
        }

        // ---- cvt + scatter vb -> sb ----
#pragma unroll
        for (int it = 0; it < 14; ++it) {
            int f4 = it * 256 + tid;
            int i  = f4 / 28;
            int q  = f4 % 28;
            int hl = q / 7;
            int w4 = q % 7;
            short* buf = sb[hl];
#pragma unroll
            for (int e = 0; e < 4; ++e) {
                int wt   = w4 * 4 + e + 1;       // 1..28
                int sidx = wt * CIN_ + ((((i >> 3) ^ (wt & 15)) << 3) | (i & 7));
                buf[sidx] = f2bf(vb[it][e]);
            }
        }

        // ---- prefetch group g+1 (stays in flight across the barrier) ----
        if (g < 6) {
            const float* xg = xb + (g + 1) * (4 * W_);
#pragma unroll
            for (int it = 0; it < 14; ++it) {
                int f4 = it * 256 + tid;
                int i  = f4 / 28;
                int q  = f4 % 28;
                vb[it] = *reinterpret_cast<const f32x4*>(xg + i * (H_ * W_) + q * 4);
            }
            __builtin_amdgcn_sched_barrier(0);
        }

        // ---- barrier 1: staging visible; prefetch NOT drained ----
        asm volatile("s_waitcnt lgkmcnt(0)" ::: "memory");
        __builtin_amdgcn_sched_barrier(0);
        __builtin_amdgcn_s_barrier();
        __builtin_amdgcn_sched_barrier(0);

        // ---- per-wave GEMM: 2 M x 2 N x 12 K-chunks (24 B-reads) ----
        f32x4 acc[2][2];
#pragma unroll
        for (int mt = 0; mt < 2; ++mt)
#pragma unroll
            for (int nt = 0; nt < 2; ++nt)
#pragma unroll
                for (int q = 0; q < 4; ++q) acc[mt][nt][q] = 0.0f;

        short* wbuf = sb[wv];
#pragma unroll
        for (int hk = 0; hk < 12; ++hk) {
            int tap = hk >> 2;
            int c   = (hk & 3) * 4 + (l >> 4);
#pragma unroll
            for (int nt = 0; nt < 2; ++nt) {
                int wt  = nt * 16 + (l & 15) + tap;   // 0..33
                int wtc = wt > 29 ? 29 : wt;          // rows >29 feed dead cols
                const short8 bfrag = *reinterpret_cast<const short8*>(
                    &wbuf[wtc * CIN_ + ((c ^ (wtc & 15)) << 3)]);
                acc[0][nt] = __builtin_amdgcn_mfma_f32_16x16x32_bf16(
                    afrag[0][hk], bfrag, acc[0][nt], 0, 0, 0);
                acc[1][nt] = __builtin_amdgcn_mfma_f32_16x16x32_bf16(
                    afrag[1][hk], bfrag, acc[1][nt], 0, 0, 0);
            }
        }

        // ---- barrier 2: own ds_reads drained; all waves done with sb ----
        asm volatile("s_waitcnt lgkmcnt(0)" ::: "memory");
        __builtin_amdgcn_sched_barrier(0);
        __builtin_amdgcn_s_barrier();
        __builtin_amdgcn_sched_barrier(0);

        // ---- gather acc -> arr[j 0..31][hl 0..3][w 0..27] (reuse sb) ----
        float* arr = reinterpret_cast<float*>(&sb[0][0]);    // 14336 B
#pragma unroll
        for (int mt = 0; mt < 2; ++mt)
#pragma unroll
            for (int nt = 0; nt < 2; ++nt)
#pragma unroll
                for (int rr = 0; rr < 4; ++rr) {
                    int j    = mt * 16 + (l >> 4) * 4 + rr;
                    int wcol = nt * 16 + (l & 15);
                    if (wcol < W_)
                        arr[(j * 4 + wv) * W_ + wcol] = acc[mt][nt][rr];
                }
        asm volatile("s_waitcnt lgkmcnt(0)" ::: "memory");
        __builtin_amdgcn_sched_barrier(0);
        __builtin_amdgcn_s_barrier();
        __builtin_amdgcn_sched_barrier(0);

        // ---- cooperative aligned f32x4 stores (with per-chunk roll) ----
#pragma unroll
        for (int it = 0; it < 4; ++it) {
            int cc = it * 256 + tid;             // 0..1023, valid < 896
            if (cc < 896) {
                int j  = cc / 28;                // cout
                int q  = cc % 28;
                int hl = q / 7;                  // local row
                int w4 = q % 7;
                int ho = h0 + hl + 1;
                if (ho >= H_) ho -= H_;
                f32x4 v = *reinterpret_cast<const f32x4*>(&arr[(j * 4 + hl) * W_ + w4 * 4]);
                *reinterpret_cast<f32x4*>(ob + (j * H_ + ho) * W_ + w4 * 4) = v;
            }
        }
        // next iteration's own lgkmcnt(0)+barrier protects arr reads before
        // any wave re-stages into this buffer (g+2 parity).
    }
}

extern "C" void kernel_launch(void* const* d_in, const int* in_sizes, int n_in,
                              void* d_out, int out_size, void* d_ws, size_t ws_size,
                              hipStream_t stream) {
    (void)in_sizes; (void)n_in; (void)out_size;
    const float* x = (const float*)d_in[0];
    const float* w = (const float*)d_in[1];
    float* out = (float*)d_out;

    if (ws_size >= (size_t)(24 * 512 * sizeof(short))) {
        short* wsA = (short*)d_ws;
        prep_w_kernel<<<dim3(48), dim3(256), 0, stream>>>(w, wsA);
        conv_kernel<true><<<dim3(B_), dim3(256), 0, stream>>>(x, w, wsA, out);
    } else {
        conv_kernel<false><<<dim3(B_), dim3(256), 0, stream>>>(x, w, (const short*)nullptr, out);
    }
}

// Round 8
// 56.980 us; speedup vs baseline: 5.5245x; 5.5245x over previous
//
#include <hip/hip_runtime.h>
#include <hip/hip_bf16.h>

// Problem constants (match reference)
#define CIN_  128
#define H_    28
#define W_    28
#define COUT_ 32
#define B_    512
// GEMM view per (b,h): Y[32 x 28] = Wm[32 x 384] * Xwin[384 x 28]
// K order: kappa = tap*128 + channel, chunked in 12 chunks of 32.

typedef __attribute__((ext_vector_type(8))) short short8;  // 8 bf16 in 4 VGPRs
typedef __attribute__((ext_vector_type(4))) float f32x4;

__device__ __forceinline__ unsigned short f2bfu(float f) {
    union { float f; unsigned u; } v; v.f = f;
    unsigned u = v.u + 0x7fffu + ((v.u >> 16) & 1u);   // RNE to bf16
    return (unsigned short)(u >> 16);
}
__device__ __forceinline__ short f2bf(float f) {
    return (short)f2bfu(f);
}

// ---------------------------------------------------------------------------
// Pre-pass: build bf16 A-fragments of Wm in d_ws.
// Fragment f = mt*12 + kc  (mt: 0..1 M-tile of 16 couts, kc: 0..11 K-chunk of 32)
// Element (lane l, slot j): Wm[jo = mt*16 + (l&15)][i = (kc&3)*32 + (l>>4)*8 + j][tap = kc>>2]
// Stored flat: ws[f*512 + l*8 + j]  -> lane l loads 16B at f*1024 + l*16 bytes.
// ---------------------------------------------------------------------------
__global__ void prep_w_kernel(const float* __restrict__ w, short* __restrict__ wsA) {
    int t = blockIdx.x * 256 + threadIdx.x;      // 24*512 = 12288 threads
    int frag = t >> 9;
    int rem  = t & 511;
    int l = rem >> 3;
    int j = rem & 7;
    int mt = frag / 12;
    int kc = frag % 12;
    int tap = kc >> 2;
    int i  = (kc & 3) * 32 + (l >> 4) * 8 + j;
    int jo = mt * 16 + (l & 15);
    wsA[t] = f2bf(w[(jo * CIN_ + i) * 3 + tap]);
}

// ---------------------------------------------------------------------------
// Main kernel v8 = R4 structure + packed-b32 staging.
// grid (7, 512), block 256 (4 waves). Wave wv computes row h = hg*4 + wv.
// Staging: each thread owns (channel-pair 2c/2c+1, w-quad q) -> two coalesced
// f32x4 loads; channels i and i+1 (i even) are ADJACENT shorts in the same
// 4-B LDS word of the swizzled layout, so each (e) packs to one ds_write_b32:
// 28 b32 writes + 28 pk-cvts per thread (was 56 b16 writes + 56 cvts).
// LDS per wave: x-row transposed [wt 0..29][128 ch] bf16, XOR-swizzled:
//   (wt, i) at short index  wt*128 + (((i>>3) ^ (wt&15))<<3 | (i&7))
// wt = w + tap (w_real = wt-1). Rows 0 and 29 zeroed (padding). B-reads with
// wt in 30..33 only feed discarded output cols (wcol >= 28); clamp to 29.
// ---------------------------------------------------------------------------
template<bool USE_WS>
__global__ __launch_bounds__(256, 5)
void conv_kernel(const float* __restrict__ x, const float* __restrict__ w,
                 const short* __restrict__ wsA, float* __restrict__ out) {
    __shared__ short lds[4][30 * CIN_];          // 4 x 7680 B = 30720 B
    const int tid = threadIdx.x;
    const int wv  = tid >> 6;
    const int l   = tid & 63;
    const int hg  = blockIdx.x;                  // 0..6
    const int b   = blockIdx.y;                  // 0..511
    const int h0  = hg * 4;

    const float* xb = x + (size_t)b * (CIN_ * H_ * W_);

    // ---- zero pad rows wt=0 and wt=29 in this wave's buffer ----
    {
        int s   = (tid & 63) * 4;                // 0..252
        int row = (s >= 128) ? 29 : 0;
        int c   = s & 127;
        *reinterpret_cast<ulong1*>(&lds[wv][row * CIN_ + c]) = ulong1{0};
    }

    // ---- staging loads: 64 channel-pairs x 28 quads; 2 f32x4 per thread-iter
    f32x4 v0[7], v1[7];
#pragma unroll
    for (int it = 0; it < 7; ++it) {
        int f4 = it * 256 + tid;                 // 0..1791
        int c  = f4 / 28;                        // channel pair 0..63
        int q  = f4 % 28;                        // quad within 448-B segment
        const float* p = xb + (2 * c) * (H_ * W_) + h0 * W_ + q * 4;
        v0[it] = *reinterpret_cast<const f32x4*>(p);
        v1[it] = *reinterpret_cast<const f32x4*>(p + H_ * W_);
    }

    // ---- packed cvt + b32 scatter into LDS ----
#pragma unroll
    for (int it = 0; it < 7; ++it) {
        int f4 = it * 256 + tid;
        int c  = f4 / 28;
        int q  = f4 % 28;
        int hl = q / 7;                          // local row 0..3
        int w4 = q % 7;
        int* buf = reinterpret_cast<int*>(&lds[hl][0]);
#pragma unroll
        for (int e = 0; e < 4; ++e) {
            int wt  = w4 * 4 + e + 1;            // 1..28
            // int-index: wt*64 + (((c>>2) ^ (wt&15))<<2) + (c&3)
            int idx = wt * 64 + ((((c >> 2) ^ (wt & 15)) << 2) | (c & 3));
            unsigned word = (unsigned)f2bfu(v0[it][e]) |
                            ((unsigned)f2bfu(v1[it][e]) << 16);
            buf[idx] = (int)word;
        }
    }
    __syncthreads();

    // ---- per-wave GEMM: 2 M-tiles x 2 N-tiles x 12 K-chunks of 32 ----
    short* wbuf = lds[wv];
    const int h = h0 + wv;

    f32x4 acc[2][2];
#pragma unroll
    for (int mt = 0; mt < 2; ++mt)
#pragma unroll
        for (int nt = 0; nt < 2; ++nt)
#pragma unroll
            for (int q = 0; q < 4; ++q) acc[mt][nt][q] = 0.0f;

#pragma unroll
    for (int half = 0; half < 2; ++half) {
        short8 a0[6], a1[6];                     // 12 frags live = 48 VGPR
        if (USE_WS) {
#pragma unroll
            for (int k6 = 0; k6 < 6; ++k6) {
                int kc = half * 6 + k6;
                a0[k6] = *reinterpret_cast<const short8*>(wsA + kc * 512 + l * 8);
                a1[k6] = *reinterpret_cast<const short8*>(wsA + (12 + kc) * 512 + l * 8);
            }
        } else {
#pragma unroll
            for (int k6 = 0; k6 < 6; ++k6) {
                int kc  = half * 6 + k6;
                int tap = kc >> 2;
                int ib  = (kc & 3) * 32 + (l >> 4) * 8;
#pragma unroll
                for (int j = 0; j < 8; ++j) {
                    a0[k6][j] = f2bf(w[((l & 15) * CIN_ + ib + j) * 3 + tap]);
                    a1[k6][j] = f2bf(w[((16 + (l & 15)) * CIN_ + ib + j) * 3 + tap]);
                }
            }
        }
#pragma unroll
        for (int k6 = 0; k6 < 6; ++k6) {
            int kc  = half * 6 + k6;
            int tap = kc >> 2;
            int c   = (kc & 3) * 4 + (l >> 4);   // chunk index of lane's 8 channels
#pragma unroll
            for (int nt = 0; nt < 2; ++nt) {
                int wt  = nt * 16 + (l & 15) + tap;     // 0..33
                int wtc = wt > 29 ? 29 : wt;            // clamp: rows >29 feed dead cols
                const short8 bfrag = *reinterpret_cast<const short8*>(
                    &wbuf[wtc * CIN_ + ((c ^ (wtc & 15)) << 3)]);
                acc[0][nt] = __builtin_amdgcn_mfma_f32_16x16x32_bf16(
                    a0[k6], bfrag, acc[0][nt], 0, 0, 0);
                acc[1][nt] = __builtin_amdgcn_mfma_f32_16x16x32_bf16(
                    a1[k6], bfrag, acc[1][nt], 0, 0, 0);
            }
        }
    }

    // ---- store with roll: y row h -> out row (h+1)%28 ----
    float* ob = out + (size_t)b * (COUT_ * H_ * W_);
    const int ho = (h + 1 == H_) ? 0 : (h + 1);
#pragma unroll
    for (int mt = 0; mt < 2; ++mt)
#pragma unroll
        for (int nt = 0; nt < 2; ++nt)
#pragma unroll
            for (int rr = 0; rr < 4; ++rr) {
                int j    = mt * 16 + (l >> 4) * 4 + rr;
                int wcol = nt * 16 + (l & 15);
                if (wcol < W_)
                    ob[(j * H_ + ho) * W_ + wcol] = acc[mt][nt][rr];
            }
}

extern "C" void kernel_launch(void* const* d_in, const int* in_sizes, int n_in,
                              void* d_out, int out_size, void* d_ws, size_t ws_size,
                              hipStream_t stream) {
    (void)in_sizes; (void)n_in; (void)out_size;
    const float* x = (const float*)d_in[0];
    const float* w = (const float*)d_in[1];
    float* out = (float*)d_out;

    if (ws_size >= (size_t)(24 * 512 * sizeof(short))) {
        short* wsA = (short*)d_ws;
        prep_w_kernel<<<dim3(48), dim3(256), 0, stream>>>(w, wsA);
        conv_kernel<true><<<dim3(7, 512), dim3(256), 0, stream>>>(x, w, wsA, out);
    } else {
        conv_kernel<false><<<dim3(7, 512), dim3(256), 0, stream>>>(x, w, (const short*)nullptr, out);
    }
}

// Round 9
// 55.728 us; speedup vs baseline: 5.6486x; 1.0225x over previous
//
#include <hip/hip_runtime.h>
#include <hip/hip_bf16.h>

// Problem constants (match reference)
#define CIN_  128
#define H_    28
#define W_    28
#define COUT_ 32
#define B_    512
// GEMM view per (b,h): Y[32 x 28] = Wm[32 x 384] * Xwin[384 x 28]
// K order: kappa = tap*128 + channel, chunked in 12 chunks of 32.

typedef __attribute__((ext_vector_type(8))) short short8;  // 8 bf16 in 4 VGPRs
typedef __attribute__((ext_vector_type(4))) float f32x4;

__device__ __forceinline__ unsigned short f2bfu(float f) {
    union { __hip_bfloat16 h; unsigned short s; } u;
    u.h = __float2bfloat16(f);                 // RNE, single HW cvt
    return u.s;
}
__device__ __forceinline__ short f2bf(float f) { return (short)f2bfu(f); }

// ---------------------------------------------------------------------------
// Pre-pass: build bf16 A-fragments of Wm in d_ws.
// Fragment f = mt*12 + kc  (mt: 0..1 M-tile of 16 couts, kc: 0..11 K-chunk of 32)
// Element (lane l, slot j): Wm[jo = mt*16 + (l&15)][i = (kc&3)*32 + (l>>4)*8 + j][tap = kc>>2]
// Stored flat: ws[f*512 + l*8 + j]  -> lane l loads 16B at f*1024 + l*16 bytes.
// ---------------------------------------------------------------------------
__global__ void prep_w_kernel(const float* __restrict__ w, short* __restrict__ wsA) {
    int t = blockIdx.x * 256 + threadIdx.x;      // 24*512 = 12288 threads
    int frag = t >> 9;
    int rem  = t & 511;
    int l = rem >> 3;
    int j = rem & 7;
    int mt = frag / 12;
    int kc = frag % 12;
    int tap = kc >> 2;
    int i  = (kc & 3) * 32 + (l >> 4) * 8 + j;
    int jo = mt * 16 + (l & 15);
    wsA[t] = f2bf(w[(jo * CIN_ + i) * 3 + tap]);
}

// ---------------------------------------------------------------------------
// Main kernel v9 = R8 + hl-aware bank swizzle + pre-barrier A-frag issue.
// grid (7, 512), block 256 (4 waves). Wave wv computes row h = hg*4 + wv.
// Staging: thread owns (channel-pair c = 2ch/2ch+1, w-quad q): two coalesced
// f32x4 loads; the pair packs into one b32 LDS word.
// LDS word layout (int units, within row-buffer hl):
//   word(wt, c) at  wt*64 + (((c>>2) ^ (wt&15) ^ hl) << 2 | (c&3))
// The ^hl term spreads the 4 row-buffers across bank-quads: without it, all
// hl and the w4-repetition (4*w4 mod 8 in {0,4}) pile ~8 lanes per bank on
// every staging write (~2.9x cost per m136). With it: counts 4,4,4,4,3,3,3,3
// over the 8 bank-quads -> ~2-way residual (free).
// Read side (wave wv = hl): B-frag chunk cch (8 channels) of row wtc is the
// b128 at short index  wtc*128 + ((cch ^ (wtc&15) ^ wv) << 3).
// wt = w + tap (w_real = wt-1). Rows 0 and 29 zeroed (padding). B-reads with
// wt in 30..33 only feed discarded output cols (wcol >= 28); clamp to 29.
// A-frag half-0 loads are issued BEFORE __syncthreads: the barrier's vmcnt
// drain completes them for free, removing L2 latency from the post-barrier
// critical path (vb registers are dead by then -> no added pressure).
// ---------------------------------------------------------------------------
template<bool USE_WS>
__global__ __launch_bounds__(256, 5)
void conv_kernel(const float* __restrict__ x, const float* __restrict__ w,
                 const short* __restrict__ wsA, float* __restrict__ out) {
    __shared__ short lds[4][30 * CIN_];          // 4 x 7680 B = 30720 B
    const int tid = threadIdx.x;
    const int wv  = tid >> 6;
    const int l   = tid & 63;
    const int hg  = blockIdx.x;                  // 0..6
    const int b   = blockIdx.y;                  // 0..511
    const int h0  = hg * 4;

    const float* xb = x + (size_t)b * (CIN_ * H_ * W_);

    // ---- zero pad rows wt=0 and wt=29 in this wave's buffer ----
    {
        int s   = (tid & 63) * 4;                // 0..252
        int row = (s >= 128) ? 29 : 0;
        int c   = s & 127;
        *reinterpret_cast<ulong1*>(&lds[wv][row * CIN_ + c]) = ulong1{0};
    }

    // ---- staging loads: 64 channel-pairs x 28 quads; 2 f32x4 per thread-iter
    f32x4 v0[7], v1[7];
#pragma unroll
    for (int it = 0; it < 7; ++it) {
        int f4 = it * 256 + tid;                 // 0..1791
        int c  = f4 / 28;                        // channel pair 0..63
        int q  = f4 % 28;                        // quad within 448-B segment
        const float* p = xb + (2 * c) * (H_ * W_) + h0 * W_ + q * 4;
        v0[it] = *reinterpret_cast<const f32x4*>(p);
        v1[it] = *reinterpret_cast<const f32x4*>(p + H_ * W_);
    }

    // ---- packed cvt + b32 scatter into LDS (hl-aware swizzle) ----
#pragma unroll
    for (int it = 0; it < 7; ++it) {
        int f4 = it * 256 + tid;
        int c  = f4 / 28;
        int q  = f4 % 28;
        int hl = q / 7;                          // local row 0..3
        int w4 = q % 7;
        int* buf = reinterpret_cast<int*>(&lds[hl][0]);
#pragma unroll
        for (int e = 0; e < 4; ++e) {
            int wt  = w4 * 4 + e + 1;            // 1..28
            int idx = wt * 64 + ((((c >> 2) ^ (wt & 15) ^ hl) << 2) | (c & 3));
            unsigned word = (unsigned)f2bfu(v0[it][e]) |
                            ((unsigned)f2bfu(v1[it][e]) << 16);
            buf[idx] = (int)word;
        }
    }

    // ---- A fragments, first K-half: ISSUE before the barrier ----
    short8 a0[6], a1[6];
    if (USE_WS) {
#pragma unroll
        for (int k6 = 0; k6 < 6; ++k6) {
            a0[k6] = *reinterpret_cast<const short8*>(wsA + k6 * 512 + l * 8);
            a1[k6] = *reinterpret_cast<const short8*>(wsA + (12 + k6) * 512 + l * 8);
        }
    } else {
#pragma unroll
        for (int k6 = 0; k6 < 6; ++k6) {
            int tap = k6 >> 2;
            int ib  = (k6 & 3) * 32 + (l >> 4) * 8;
#pragma unroll
            for (int j = 0; j < 8; ++j) {
                a0[k6][j] = f2bf(w[((l & 15) * CIN_ + ib + j) * 3 + tap]);
                a1[k6][j] = f2bf(w[((16 + (l & 15)) * CIN_ + ib + j) * 3 + tap]);
            }
        }
    }
    __syncthreads();   // drains lgkm (staging) AND vmcnt (a-frags) for free

    // ---- per-wave GEMM: 2 M-tiles x 2 N-tiles x 12 K-chunks of 32 ----
    short* wbuf = lds[wv];
    const int h = h0 + wv;

    f32x4 acc[2][2];
#pragma unroll
    for (int mt = 0; mt < 2; ++mt)
#pragma unroll
        for (int nt = 0; nt < 2; ++nt)
#pragma unroll
            for (int q = 0; q < 4; ++q) acc[mt][nt][q] = 0.0f;

#pragma unroll
    for (int half = 0; half < 2; ++half) {
        if (half == 1) {                         // reload A frags, second K-half
            if (USE_WS) {
#pragma unroll
                for (int k6 = 0; k6 < 6; ++k6) {
                    int kc = 6 + k6;
                    a0[k6] = *reinterpret_cast<const short8*>(wsA + kc * 512 + l * 8);
                    a1[k6] = *reinterpret_cast<const short8*>(wsA + (12 + kc) * 512 + l * 8);
                }
            } else {
#pragma unroll
                for (int k6 = 0; k6 < 6; ++k6) {
                    int kc  = 6 + k6;
                    int tap = kc >> 2;
                    int ib  = (kc & 3) * 32 + (l >> 4) * 8;
#pragma unroll
                    for (int j = 0; j < 8; ++j) {
                        a0[k6][j] = f2bf(w[((l & 15) * CIN_ + ib + j) * 3 + tap]);
                        a1[k6][j] = f2bf(w[((16 + (l & 15)) * CIN_ + ib + j) * 3 + tap]);
                    }
                }
            }
        }
#pragma unroll
        for (int k6 = 0; k6 < 6; ++k6) {
            int kc  = half * 6 + k6;
            int tap = kc >> 2;
            int cch = (kc & 3) * 4 + (l >> 4);   // chunk index of lane's 8 channels
#pragma unroll
            for (int nt = 0; nt < 2; ++nt) {
                int wt  = nt * 16 + (l & 15) + tap;     // 0..33
                int wtc = wt > 29 ? 29 : wt;            // clamp: rows >29 feed dead cols
                const short8 bfrag = *reinterpret_cast<const short8*>(
                    &wbuf[wtc * CIN_ + ((cch ^ (wtc & 15) ^ wv) << 3)]);
                acc[0][nt] = __builtin_amdgcn_mfma_f32_16x16x32_bf16(
                    a0[k6], bfrag, acc[0][nt], 0, 0, 0);
                acc[1][nt] = __builtin_amdgcn_mfma_f32_16x16x32_bf16(
                    a1[k6], bfrag, acc[1][nt], 0, 0, 0);
            }
        }
    }

    // ---- store with roll: y row h -> out row (h+1)%28 ----
    float* ob = out + (size_t)b * (COUT_ * H_ * W_);
    const int ho = (h + 1 == H_) ? 0 : (h + 1);
#pragma unroll
    for (int mt = 0; mt < 2; ++mt)
#pragma unroll
        for (int nt = 0; nt < 2; ++nt)
#pragma unroll
            for (int rr = 0; rr < 4; ++rr) {
                int j    = mt * 16 + (l >> 4) * 4 + rr;
                int wcol = nt * 16 + (l & 15);
                if (wcol < W_)
                    ob[(j * H_ + ho) * W_ + wcol] = acc[mt][nt][rr];
            }
}

extern "C" void kernel_launch(void* const* d_in, const int* in_sizes, int n_in,
                              void* d_out, int out_size, void* d_ws, size_t ws_size,
                              hipStream_t stream) {
    (void)in_sizes; (void)n_in; (void)out_size;
    const float* x = (const float*)d_in[0];
    const float* w = (const float*)d_in[1];
    float* out = (float*)d_out;

    if (ws_size >= (size_t)(24 * 512 * sizeof(short))) {
        short* wsA = (short*)d_ws;
        prep_w_kernel<<<dim3(48), dim3(256), 0, stream>>>(w, wsA);
        conv_kernel<true><<<dim3(7, 512), dim3(256), 0, stream>>>(x, w, wsA, out);
    } else {
        conv_kernel<false><<<dim3(7, 512), dim3(256), 0, stream>>>(x, w, (const short*)nullptr, out);
    }
}